// Round 12
// baseline (367.681 us; speedup 1.0000x reference)
//
#include <hip/hip_runtime.h>
#include <math.h>

typedef _Float16 f16;
typedef __attribute__((ext_vector_type(8))) _Float16 f16x8;
typedef __attribute__((ext_vector_type(4))) _Float16 f16x4;
typedef __attribute__((ext_vector_type(4))) float f32x4;
typedef __attribute__((ext_vector_type(16))) float f32x16;
typedef __attribute__((ext_vector_type(2))) __fp16 h16x2;

#define QSCALE 0.1803368801111204f  /* 0.125 * log2(e) */

__device__ __forceinline__ void gl_lds16(const f16* g, f16* l) {
    __builtin_amdgcn_global_load_lds((const __attribute__((address_space(1))) void*)g,
                                     (__attribute__((address_space(3))) void*)l, 16, 0, 0);
}

// ---------------------------------------------------------------------------
// Mega prep kernel: 8 square weight transposes + w1 + w2 transposes + 2 cvts.
// ---------------------------------------------------------------------------
struct PrepArgs {
    const float* ws[10]; f16* wd[10];
    const float* x; f16* xh;
    const float* cross; f16* ch;
};
__global__ __launch_bounds__(256)
void prep_all(PrepArgs p) {
    __shared__ float t[32][33];
    int bid = blockIdx.x, tid = threadIdx.x;
    if (bid < 4096) {
        const float* W; f16* Wt; int K, N, nx, ky;
        if (bid < 2048) {
            int wi = bid >> 8, tl = bid & 255;
            W = p.ws[wi]; Wt = p.wd[wi]; K = 512; N = 512; nx = tl & 15; ky = tl >> 4;
        } else if (bid < 3072) {
            int tl = bid - 2048;
            W = p.ws[8]; Wt = p.wd[8]; K = 512; N = 2048; nx = tl & 63; ky = tl >> 6;
        } else {
            int tl = bid - 3072;
            W = p.ws[9]; Wt = p.wd[9]; K = 2048; N = 512; nx = tl & 15; ky = tl >> 4;
        }
        int tx = tid & 31, ty = tid >> 5;
        int n0 = nx * 32, k0 = ky * 32;
#pragma unroll
        for (int i = 0; i < 4; i++)
            t[ty + i * 8][tx] = W[(size_t)(k0 + ty + i * 8) * N + n0 + tx];
        __syncthreads();
#pragma unroll
        for (int i = 0; i < 4; i++)
            Wt[(size_t)(n0 + ty + i * 8) * K + k0 + tx] = (f16)t[tx][ty + i * 8];
    } else {
        const float* X; f16* Y; size_t cb;
        if (bid < 6144) { X = p.x; Y = p.xh; cb = bid - 4096; }
        else            { X = p.cross; Y = p.ch; cb = bid - 6144; }
        size_t i = (cb * 256 + tid) * 4;
        f32x4 v = *(const f32x4*)(X + i);
        f16x4 o;
        o[0] = (f16)v[0]; o[1] = (f16)v[1]; o[2] = (f16)v[2]; o[3] = (f16)v[3];
        *(f16x4*)(Y + i) = o;
    }
}

// ---------------------------------------------------------------------------
// LayerNorm D=512, f32 in -> f16 out. 1 block (128 thr) per row.
// ---------------------------------------------------------------------------
__global__ __launch_bounds__(128)
void layernorm_f16(const float* __restrict__ X, const float* __restrict__ g,
                   const float* __restrict__ bta, f16* __restrict__ Y)
{
    __shared__ float red[4];
    int row = blockIdx.x;
    int tid = threadIdx.x;
    const float* x = X + (size_t)row * 512;
    f32x4 v = *(const f32x4*)(x + tid * 4);
    float s  = v[0] + v[1] + v[2] + v[3];
    float ss = v[0] * v[0] + v[1] * v[1] + v[2] * v[2] + v[3] * v[3];
#pragma unroll
    for (int m = 1; m < 64; m <<= 1) {
        s  += __shfl_xor(s, m, 64);
        ss += __shfl_xor(ss, m, 64);
    }
    int wave = tid >> 6, lane = tid & 63;
    if (lane == 0) { red[wave * 2] = s; red[wave * 2 + 1] = ss; }
    __syncthreads();
    s = red[0] + red[2]; ss = red[1] + red[3];
    float mu  = s * (1.0f / 512);
    float var = ss * (1.0f / 512) - mu * mu;
    float inv = rsqrtf(var + 1e-5f);
    f32x4 gv = *(const f32x4*)(g + tid * 4);
    f32x4 bv = *(const f32x4*)(bta + tid * 4);
    f16x4 o;
#pragma unroll
    for (int i = 0; i < 4; i++) o[i] = (f16)((v[i] - mu) * inv * gv[i] + bv[i]);
    *(f16x4*)(Y + (size_t)row * 512 + tid * 4) = o;
}

// ---------------------------------------------------------------------------
// GEMM 128x128 tile, BK=64, DOUBLE-BUFFERED LDS, XOR-swizzled rows.
// vtp/vseg: V output segment written TRANSPOSED [bh][64][NB] (fused transpose).
// Kstride: row stride of A/Wt (> K enables K-slicing via blockIdx.z).
// zsl: if nonzero, Cf32 += blockIdx.z * zsl and raw acc is written.
// FUSED 2nd GEMM (r12): if nblk1 > 0, grid is FLAT 1-D; blocks >= nblk1 run
// a second independent gemm (A2 @ Wt2 + b0q -> head-major hmq, NB=2048,
// s0=QSCALE) -- used to overlap the cross Q-projection with the KV gemm
// (they read different inputs; previously serialized as a gemm64 launch).
// ---------------------------------------------------------------------------
__global__ __launch_bounds__(256)
void gemm_f16(const f16* __restrict__ A, const f16* __restrict__ Wt,
              const float* __restrict__ b0, const float* __restrict__ b1,
              const float* __restrict__ b2, const float* __restrict__ res,
              float* __restrict__ Cf32, f16* __restrict__ C16,
              f16* __restrict__ hm0, f16* __restrict__ hm1, f16* __restrict__ hm2,
              f16* __restrict__ vtp, int vseg,
              int N, int K, int Kstride, int NBshift, int fused, int act,
              size_t zsl, float s0,
              const f16* __restrict__ A2, const f16* __restrict__ Wt2,
              const float* __restrict__ b0q, f16* __restrict__ hmq, int nblk1)
{
    __shared__ __align__(16) f16 As[2][128 * 64];
    __shared__ __align__(16) f16 Bs[2][128 * 64];
    int tid = threadIdx.x, lane = tid & 63, wave = tid >> 6;
    int quad = lane >> 4, ln16 = lane & 15;
    int wm = wave >> 1, wn = wave & 1;

    // per-block routing (wave-uniform)
    const f16* Ap = A; const f16* Wp = Wt;
    const float* b0p = b0; const float* resp = res;
    float* Cfp = Cf32; f16* C16p = C16;
    f16* hm0p = hm0; f16* vtpp = vtp;
    int Np = N, fusedp = fused, actp = act, nbs = NBshift;
    float s0p = s0;
    int bx = blockIdx.x, by = blockIdx.y;
    if (nblk1) {
        int fb = bx;
        if (fb >= nblk1) {
            int q = fb - nblk1;
            bx = q & 3; by = q >> 2;
            Ap = A2; Wp = Wt2; b0p = b0q; hm0p = hmq;
            vtpp = nullptr; Cfp = nullptr; C16p = nullptr; resp = nullptr;
            Np = 512; fusedp = 0; actp = 0; nbs = 11; s0p = QSCALE;
        } else {
            bx = fb & 7; by = fb >> 3;
        }
    }
    int bm0 = by * 128, bn0 = bx * 128;
    int kz = blockIdx.z * K;
    if (zsl) Cfp += blockIdx.z * zsl;

    f32x4 acc[4][4];
#pragma unroll
    for (int i = 0; i < 4; i++)
#pragma unroll
        for (int j = 0; j < 4; j++) acc[i][j] = (f32x4){0.f, 0.f, 0.f, 0.f};

    const f16* ag[4]; const f16* bg[4]; int Loff[4];
#pragma unroll
    for (int j = 0; j < 4; j++) {
        int L = tid + j * 256;
        int row = L >> 3, cc = (L & 7) ^ (row & 7);
        ag[j] = Ap + (size_t)(bm0 + row) * Kstride + kz + cc * 8;
        bg[j] = Wp + (size_t)(bn0 + row) * Kstride + kz + cc * 8;
        Loff[j] = L * 8;
    }
    int sw0 = (quad ^ (ln16 & 7)) * 8, sw1 = ((4 + quad) ^ (ln16 & 7)) * 8;

    // prologue
#pragma unroll
    for (int j = 0; j < 4; j++) { gl_lds16(ag[j], &As[0][Loff[j]]); gl_lds16(bg[j], &Bs[0][Loff[j]]); }
#pragma unroll
    for (int j = 0; j < 4; j++) { ag[j] += 64; bg[j] += 64; }

    int cur = 0;
    for (int kt = 0; kt < K; kt += 64) {
        __syncthreads();
        if (kt + 64 < K) {
            int nxt = cur ^ 1;
#pragma unroll
            for (int j = 0; j < 4; j++) { gl_lds16(ag[j], &As[nxt][Loff[j]]); gl_lds16(bg[j], &Bs[nxt][Loff[j]]); }
#pragma unroll
            for (int j = 0; j < 4; j++) { ag[j] += 64; bg[j] += 64; }
        }
        const f16* Ac = As[cur]; const f16* Bc = Bs[cur];
#pragma unroll
        for (int h = 0; h < 2; h++) {
            int sw = h ? sw1 : sw0;
            f16x8 af[4], bf[4];
#pragma unroll
            for (int mt = 0; mt < 4; mt++)
                af[mt] = *(const f16x8*)&Ac[(wm * 64 + mt * 16 + ln16) * 64 + sw];
#pragma unroll
            for (int nt = 0; nt < 4; nt++)
                bf[nt] = *(const f16x8*)&Bc[(wn * 64 + nt * 16 + ln16) * 64 + sw];
#pragma unroll
            for (int mt = 0; mt < 4; mt++)
#pragma unroll
                for (int nt = 0; nt < 4; nt++)
                    acc[mt][nt] = __builtin_amdgcn_mfma_f32_16x16x32_f16(af[mt], bf[nt], acc[mt][nt], 0, 0, 0);
        }
        cur ^= 1;
    }

    int NB = 1 << nbs;
#pragma unroll
    for (int mt = 0; mt < 4; mt++) {
#pragma unroll
        for (int nt = 0; nt < 4; nt++) {
            int row = bm0 + wm * 64 + mt * 16 + quad * 4;
            int col = bn0 + wn * 64 + nt * 16 + ln16;
            if (zsl) {
#pragma unroll
                for (int i = 0; i < 4; i++)
                    Cfp[(size_t)(row + i) * Np + col] = acc[mt][nt][i];
                continue;
            }
            float bv;
            if (fusedp) {
                int seg = col >> 9;
                const float* bp = seg == 0 ? b0p : (seg == 1 ? b1 : b2);
                bv = bp[col & 511];
            } else bv = b0p[col];
            int seg = col >> 9;
            if (vtpp && seg == vseg) {
                // V segment: write transposed [bh][64][NB], 4 tokens per store
                int hh = (col >> 6) & 7, d = col & 63;
                int bt = row >> nbs, rr = row & (NB - 1);
                f16x4 o4;
#pragma unroll
                for (int i = 0; i < 4; i++) o4[i] = (f16)(acc[mt][nt][i] + bv);
                *(f16x4*)&vtpp[(((size_t)bt * 8 + hh) * 64 + d) * NB + rr] = o4;
            } else {
#pragma unroll
                for (int i = 0; i < 4; i++) {
                    int r = row + i;
                    float v = acc[mt][nt][i] + bv;
                    size_t idx = (size_t)r * Np + col;
                    if (resp) v += resp[idx];
                    if (actp) v = 0.5f * v * (1.0f + erff(v * 0.70710678118654752f));
                    if (Cfp) Cfp[idx] = v;
                    if (C16p) C16p[idx] = (f16)v;
                    if (hm0p) {
                        f16* hp = seg == 0 ? hm0p : (seg == 1 ? hm1 : hm2);
                        float vv = seg == 0 ? v * s0p : v;
                        int hh = (col >> 6) & 7, d = col & 63;
                        int bt = r >> nbs, rr = r & (NB - 1);
                        hp[(((size_t)bt * 8 + hh) * NB + rr) * 64 + d] = (f16)vv;
                    }
                }
            }
        }
    }
}

// ---------------------------------------------------------------------------
// MLP2 combine: out = Yb + b2 + sum of 4 f32 partial slices.  Pure BW
// (~48 MB).  grid 2048 x 256, 4 f32/thread.
// ---------------------------------------------------------------------------
__global__ __launch_bounds__(256)
void mlp2_combine(const float* __restrict__ Pk, const float* __restrict__ Yb,
                  const float* __restrict__ b2, float* __restrict__ out)
{
    size_t i = ((size_t)blockIdx.x * 256 + threadIdx.x) * 4;
    int col = (int)(i & 511);
    f32x4 v = *(const f32x4*)(Yb + i);
    f32x4 bb = *(const f32x4*)(b2 + col);
#pragma unroll
    for (int s = 0; s < 4; s++) {
        f32x4 p = *(const f32x4*)(Pk + (size_t)s * 2097152 + i);
#pragma unroll
        for (int j = 0; j < 4; j++) v[j] += p[j];
    }
#pragma unroll
    for (int j = 0; j < 4; j++) v[j] += bb[j];
    *(f32x4*)(out + i) = v;
}

// ---------------------------------------------------------------------------
// GEMM 64x64 tile, BK=64, DOUBLE-BUFFERED LDS.  N=512 shapes (512 blocks).
// ---------------------------------------------------------------------------
__global__ __launch_bounds__(256)
void gemm64(const f16* __restrict__ A, const f16* __restrict__ Wt,
            const float* __restrict__ bias, const float* __restrict__ res,
            float* __restrict__ Cf32, f16* __restrict__ hm0,
            int N, int K, int NBshift, float s0)
{
    __shared__ __align__(16) f16 As[2][64 * 64];
    __shared__ __align__(16) f16 Bs[2][64 * 64];
    int tid = threadIdx.x, lane = tid & 63, wave = tid >> 6;
    int quad = lane >> 4, ln16 = lane & 15;
    int wm = wave >> 1, wn = wave & 1;
    int bm0 = blockIdx.y * 64, bn0 = blockIdx.x * 64;

    f32x4 acc[2][2];
#pragma unroll
    for (int i = 0; i < 2; i++)
#pragma unroll
        for (int j = 0; j < 2; j++) acc[i][j] = (f32x4){0.f, 0.f, 0.f, 0.f};

    const f16* ag[2]; const f16* bg[2]; int Loff[2];
#pragma unroll
    for (int j = 0; j < 2; j++) {
        int L = tid + j * 256;
        int row = L >> 3, cc = (L & 7) ^ (row & 7);
        ag[j] = A  + (size_t)(bm0 + row) * K + cc * 8;
        bg[j] = Wt + (size_t)(bn0 + row) * K + cc * 8;
        Loff[j] = L * 8;
    }
    int sw0 = (quad ^ (ln16 & 7)) * 8, sw1 = ((4 + quad) ^ (ln16 & 7)) * 8;

#pragma unroll
    for (int j = 0; j < 2; j++) { gl_lds16(ag[j], &As[0][Loff[j]]); gl_lds16(bg[j], &Bs[0][Loff[j]]); }
#pragma unroll
    for (int j = 0; j < 2; j++) { ag[j] += 64; bg[j] += 64; }

    int cur = 0;
    for (int kt = 0; kt < K; kt += 64) {
        __syncthreads();
        if (kt + 64 < K) {
            int nxt = cur ^ 1;
#pragma unroll
            for (int j = 0; j < 2; j++) { gl_lds16(ag[j], &As[nxt][Loff[j]]); gl_lds16(bg[j], &Bs[nxt][Loff[j]]); }
#pragma unroll
            for (int j = 0; j < 2; j++) { ag[j] += 64; bg[j] += 64; }
        }
        const f16* Ac = As[cur]; const f16* Bc = Bs[cur];
#pragma unroll
        for (int h = 0; h < 2; h++) {
            int sw = h ? sw1 : sw0;
            f16x8 af[2], bf[2];
#pragma unroll
            for (int mt = 0; mt < 2; mt++)
                af[mt] = *(const f16x8*)&Ac[(wm * 32 + mt * 16 + ln16) * 64 + sw];
#pragma unroll
            for (int nt = 0; nt < 2; nt++)
                bf[nt] = *(const f16x8*)&Bc[(wn * 32 + nt * 16 + ln16) * 64 + sw];
#pragma unroll
            for (int mt = 0; mt < 2; mt++)
#pragma unroll
                for (int nt = 0; nt < 2; nt++)
                    acc[mt][nt] = __builtin_amdgcn_mfma_f32_16x16x32_f16(af[mt], bf[nt], acc[mt][nt], 0, 0, 0);
        }
        cur ^= 1;
    }

    int NB = 1 << NBshift;
#pragma unroll
    for (int mt = 0; mt < 2; mt++) {
#pragma unroll
        for (int nt = 0; nt < 2; nt++) {
            int row = bm0 + wm * 32 + mt * 16 + quad * 4;
            int col = bn0 + wn * 32 + nt * 16 + ln16;
            float bv = bias[col];
#pragma unroll
            for (int i = 0; i < 4; i++) {
                int r = row + i;
                float v = acc[mt][nt][i] + bv;
                size_t idx = (size_t)r * N + col;
                if (res) v += res[idx];
                if (Cf32) Cf32[idx] = v;
                if (hm0) {
                    int hh = (col >> 6) & 7, d = col & 63;
                    int bt = r >> NBshift, rr = r & (NB - 1);
                    hm0[(((size_t)bt * 8 + hh) * NB + rr) * 64 + d] = (f16)(v * s0);
                }
            }
        }
    }
}

// ---------------------------------------------------------------------------
// Flash attention v17 (measured plateau: ~51us cross / ~26us self; v16/v17/
// v18 all equal within noise).  XCD co-location (fid&7 = head -> K/V split
// L2-resident, FETCH 67.6->10.3 MB), s_setprio around MFMA, all-32x32x16,
// raw v_exp, natural-P PV (no lane exchange; V A-frag read to match P's
// post-QK^T layout).  512 thr = 8 waves, 32 q/wave; dbuf K/V; split-K x4.
// NOTE: (512,4) caps arch+acc VGPRs at 128 total; v17 = 64+48 = 112.
// Tripwires: VGPR 64, WRITE 16.9 MB, FETCH ~10.3 MB.
// ---------------------------------------------------------------------------
__global__ __launch_bounds__(512, 4)
void attention_split(const f16* __restrict__ Qh, const f16* __restrict__ Kh,
                     const f16* __restrict__ Vt, f16* __restrict__ Op,
                     float* __restrict__ Lsum, int Nk, int nsp_log)
{
    __shared__ __align__(16) f16 Kt[2][64 * 64];
    __shared__ __align__(16) f16 Vs[2][64 * 64];
    int fid = blockIdx.x;
    int h8 = fid & 7;
    int qt = (fid >> 3) & 7;
    int z  = fid >> 6;
    int b = z >> nsp_log, sp = z & ((1 << nsp_log) - 1);
    int bh = b * 8 + h8;
    int Nkh = Nk >> nsp_log;
    int tid = threadIdx.x, lane = tid & 63, wave = tid >> 6;
    int lq = lane & 31, hh = lane >> 5, l7 = lane & 7;
    int qrow0 = qt * 256 + wave * 32;

    // Q B-frags (32x32x16): lane holds q = qrow0+lq, d = s*16 + hh*8 + (0..7)
    f16x8 qf[4];
#pragma unroll
    for (int s = 0; s < 4; s++)
        qf[s] = *(const f16x8*)(Qh + ((size_t)bh * 2048 + qrow0 + lq) * 64 + s * 16 + hh * 8);

    f32x16 oacc[2];
#pragma unroll
    for (int db = 0; db < 2; db++)
#pragma unroll
        for (int r = 0; r < 16; r++) oacc[db][r] = 0.f;
    float la[4] = {0.f, 0.f, 0.f, 0.f};

    const f16* kb = Kh + ((size_t)bh * Nk + sp * Nkh) * 64;
    const f16* vb = Vt + (size_t)bh * 64 * Nk + sp * Nkh;

    const f16* kg; const f16* vg; int Lo;
    {
        int L = tid;
        int row = L >> 3, cc = (L & 7) ^ (row & 7);
        kg = kb + (size_t)row * 64 + cc * 8;
        vg = vb + (size_t)row * Nk + cc * 8;
        Lo = L * 8;
    }

    // K read offsets (f16 units): row = kbk*32+lq, chunk = (2s+hh)^(row&7)
    int koff[2][4];
#pragma unroll
    for (int kbk = 0; kbk < 2; kbk++)
#pragma unroll
        for (int s = 0; s < 4; s++)
            koff[kbk][s] = (kbk * 32 + lq) * 64 + (((2 * s + hh) ^ l7) * 8);
    // V read base (f16 units): row = db*32+lq (d), byte-half hh -> +hh*4 f16
    int vrow0 = lq * 64 + hh * 4;

    // prologue: tile 0 -> buf 0
    gl_lds16(kg, &Kt[0][Lo]);
    gl_lds16(vg, &Vs[0][Lo]);
    kg += 64 * 64; vg += 64;

    int cur = 0;
    for (int kt = 0; kt < Nkh; kt += 64) {
        __syncthreads();
        if (kt + 64 < Nkh) {
            int nxt = cur ^ 1;
            gl_lds16(kg, &Kt[nxt][Lo]);
            gl_lds16(vg, &Vs[nxt][Lo]);
            kg += 64 * 64; vg += 64;
        }
        const f16* Ktc = Kt[cur]; const f16* Vsc = Vs[cur];

#pragma unroll
        for (int kbk = 0; kbk < 2; kbk++) {
            // ---- QK^T for 32 keys: S^T C-layout, key = kbk*32+(r&3)+8*(r>>2)+4hh
            f32x16 c;
#pragma unroll
            for (int r = 0; r < 16; r++) c[r] = 0.f;
            __builtin_amdgcn_s_setprio(1);
#pragma unroll
            for (int s = 0; s < 4; s++) {
                f16x8 kf = *(const f16x8*)&Ktc[koff[kbk][s]];
                c = __builtin_amdgcn_mfma_f32_32x32x16_f16(kf, qf[s], c, 0, 0, 0);
            }
            __builtin_amdgcn_s_setprio(0);
            // ---- exp2 + l-accumulate + pack pairs.
            // pr[m] = packed f16{e(c[2m]), e(c[2m+1])}; pair keys (this half):
            // m0:{4hh,4hh+1} m1:{4hh+2,4hh+3} m2:{8+4hh,9+4hh} m3:{10+4hh,11+4hh}
            // m4..7: +16 of m0..3.  Used DIRECTLY as MFMA B-operand below.
            int pr[8];
#pragma unroll
            for (int m = 0; m < 8; m++) {
                float e0 = __builtin_amdgcn_exp2f(c[2 * m]);
                float e1 = __builtin_amdgcn_exp2f(c[2 * m + 1]);
                la[2 * (m & 1)]     += e0;
                la[2 * (m & 1) + 1] += e1;
                union { h16x2 h; int i; } u;
                u.h = __builtin_amdgcn_cvt_pkrtz(e0, e1);
                pr[m] = u.i;
            }
            // ---- PV: B = pr[4t..4t+3] (natural layout); A (V) reads match:
            // slot j<4 = V[d][base0+j], slot j>=4 = V[d][base0+8+j-4],
            // base0 = kbk*32 + t*16 + 4hh -> chunks (kbk*4+2t) and (+1), half hh.
#pragma unroll
            for (int t = 0; t < 2; t++) {
                union { int i[4]; f16x8 v; } bu;
                bu.i[0] = pr[4 * t + 0];
                bu.i[1] = pr[4 * t + 1];
                bu.i[2] = pr[4 * t + 2];
                bu.i[3] = pr[4 * t + 3];
                int c0 = ((kbk * 4 + 2 * t) ^ l7) * 8;
                int c1 = ((kbk * 4 + 2 * t + 1) ^ l7) * 8;
                __builtin_amdgcn_s_setprio(1);
#pragma unroll
                for (int db = 0; db < 2; db++) {
                    const f16* vr = &Vsc[db * 2048 + vrow0];
                    union { f16x4 h[2]; f16x8 v; } vf;
                    vf.h[0] = *(const f16x4*)&vr[c0];
                    vf.h[1] = *(const f16x4*)&vr[c1];
                    oacc[db] = __builtin_amdgcn_mfma_f32_32x32x16_f16(vf.v, bu.v, oacc[db], 0, 0, 0);
                }
                __builtin_amdgcn_s_setprio(0);
            }
        }
        cur ^= 1;
    }

    // epilogue: lane holds q = qrow0+lq; oacc[db][r] -> d = db*32+(r&3)+8*(r>>2)+4hh
    float lacc = (la[0] + la[1]) + (la[2] + la[3]);
    float ltot = lacc + __shfl_xor(lacc, 32, 64);
    size_t rowb = ((size_t)(sp * 16 + bh) * 2048 + qrow0 + lq) * 64;
#pragma unroll
    for (int db = 0; db < 2; db++)
#pragma unroll
        for (int rq = 0; rq < 4; rq++) {
            f16x4 o4;
#pragma unroll
            for (int i = 0; i < 4; i++) o4[i] = (f16)oacc[db][rq * 4 + i];
            *(f16x4*)&Op[rowb + db * 32 + rq * 8 + hh * 4] = o4;
        }
    if (hh == 0)
        Lsum[(size_t)(sp * 16 + bh) * 2048 + qrow0 + lq] = ltot;
}

// ---------------------------------------------------------------------------
// Combine nsplit key-splits (shared implicit max -> plain sums). grid 8192x256.
// ---------------------------------------------------------------------------
__global__ __launch_bounds__(256)
void attn_combine(const f16* __restrict__ Op, const float* __restrict__ Lsum,
                  f16* __restrict__ O, int nsplit)
{
    int t = blockIdx.x * 256 + threadIdx.x;
    int d = t & 63;
    int q = (t >> 6) & 2047;
    int bh = t >> 17;
    int b = bh >> 3, h = bh & 7;
    float l = 0.f, val = 0.f;
#pragma unroll 4
    for (int s = 0; s < nsplit; s++) {
        l   += Lsum[(size_t)(s * 16 + bh) * 2048 + q];
        val += (float)Op[((size_t)(s * 16 + bh) * 2048 + q) * 64 + d];
    }
    O[((size_t)b * 2048 + q) * 512 + h * 64 + d] = (f16)(val / l);
}

// ---------------------------------------------------------------------------
extern "C" void kernel_launch(void* const* d_in, const int* in_sizes, int n_in,
                              void* d_out, int out_size, void* d_ws, size_t ws_size,
                              hipStream_t stream)
{
    (void)in_sizes; (void)n_in; (void)out_size; (void)ws_size;
    const float* x      = (const float*)d_in[0];
    const float* cross  = (const float*)d_in[1];
    const float* ca_wq  = (const float*)d_in[2];
    const float* ca_bq  = (const float*)d_in[3];
    const float* ca_wk  = (const float*)d_in[4];
    const float* ca_bk  = (const float*)d_in[5];
    const float* ca_wv  = (const float*)d_in[6];
    const float* ca_bv  = (const float*)d_in[7];
    const float* ca_wo  = (const float*)d_in[8];
    const float* ca_bo  = (const float*)d_in[9];
    const float* sa_wq  = (const float*)d_in[10];
    const float* sa_bq  = (const float*)d_in[11];
    const float* sa_wk  = (const float*)d_in[12];
    const float* sa_bk  = (const float*)d_in[13];
    const float* sa_wv  = (const float*)d_in[14];
    const float* sa_bv  = (const float*)d_in[15];
    const float* sa_wo  = (const float*)d_in[16];
    const float* sa_bo  = (const float*)d_in[17];
    const float* ln1_g  = (const float*)d_in[18];
    const float* ln1_b  = (const float*)d_in[19];
    const float* ln2_g  = (const float*)d_in[20];
    const float* ln2_b  = (const float*)d_in[21];
    const float* mlp_w1 = (const float*)d_in[22];
    const float* mlp_b1 = (const float*)d_in[23];
    const float* mlp_w2 = (const float*)d_in[24];
    const float* mlp_b2 = (const float*)d_in[25];
    float* out = (float*)d_out;

    // ---- workspace layout ----
    float* XC = (float*)d_ws;            // 2M f32
    float* Yb = XC + 2097152;            // 2M f32
    f16* fb   = (f16*)(Yb + 2097152);
    f16* xh     = fb;                    // 2M
    f16* crossh = xh + 2097152;          // 4M
    f16* xnh    = crossh + 4194304;      // 2M
    f16* xn2h   = xnh + 2097152;         // 2M
    f16* Qh     = xn2h + 2097152;        // 2M
    f16* Kh     = Qh + 2097152;          // 4M
    f16* Vh     = Kh + 4194304;          // 4M (unused; kept for layout stability)
    f16* Vtb    = Vh + 4194304;          // 4M
    f16* ctxh   = Vtb + 4194304;         // 2M
    f16* h1h    = ctxh + 2097152;        // 8M (reused as attention partials Op)
    f16* t_caq  = h1h + 8388608;
    f16* t_cak  = t_caq + 262144;
    f16* t_cav  = t_cak + 262144;
    f16* t_cao  = t_cav + 262144;
    f16* t_saq  = t_cao + 262144;
    f16* t_sak  = t_saq + 262144;
    f16* t_sav  = t_sak + 262144;
    f16* t_sao  = t_sav + 262144;
    f16* t_w1   = t_sao + 262144;        // 1M
    f16* t_w2   = t_w1 + 1048576;        // 1M
    float* Lsum = (float*)(t_w2 + 1048576);   // 131072 floats

    // MLP2 split-K partials: 4 x [4096][512] f32 = 32 MB, aliasing the dead
    // Qh..ctxh region (Qh/Kh/Vh/Vtb dead after self-attn; ctxh dead after
    // step d, which precedes MLP2).
    float* Pk = (float*)Qh;

    PrepArgs pa;
    pa.ws[0] = ca_wq; pa.wd[0] = t_caq;
    pa.ws[1] = ca_wk; pa.wd[1] = t_cak;
    pa.ws[2] = ca_wv; pa.wd[2] = t_cav;
    pa.ws[3] = ca_wo; pa.wd[3] = t_cao;
    pa.ws[4] = sa_wq; pa.wd[4] = t_saq;
    pa.ws[5] = sa_wk; pa.wd[5] = t_sak;
    pa.ws[6] = sa_wv; pa.wd[6] = t_sav;
    pa.ws[7] = sa_wo; pa.wd[7] = t_sao;
    pa.ws[8] = mlp_w1; pa.wd[8] = t_w1;
    pa.ws[9] = mlp_w2; pa.wd[9] = t_w2;
    pa.x = x; pa.xh = xh; pa.cross = cross; pa.ch = crossh;
    prep_all<<<10240, 256, 0, stream>>>(pa);

    // a) cross-attention.  FUSED launch: blocks 0-511 = K|V projection of
    // cross (fused bias, V pre-transposed), blocks 512-639 = Q projection of
    // x (head-major Qh, pre-scaled by QSCALE) -- independent gemms that were
    // previously serialized (gemm64 Q then gemm_f16 KV).
    gemm_f16<<<dim3(640), 256, 0, stream>>>(crossh, t_cak, ca_bk, ca_bv, nullptr, nullptr,
        nullptr, nullptr, Kh, nullptr, nullptr, Vtb, 1, 1024, 512, 512, 12, 1, 0, 0, 1.0f,
        xh, t_caq, ca_bq, Qh, 512);
    attention_split<<<512, 512, 0, stream>>>(Qh, Kh, Vtb, h1h, Lsum, 4096, 2);
    attn_combine<<<8192, 256, 0, stream>>>(h1h, Lsum, ctxh, 4);
    gemm64<<<dim3(8, 64), 256, 0, stream>>>(ctxh, t_cao, ca_bo, nullptr, XC, nullptr,
                                            512, 512, 11, 1.0f);
    // b,c) LN1 + self-attention (fused QKV, Q pre-scaled; split-K x4)
    layernorm_f16<<<4096, 128, 0, stream>>>(XC, ln1_g, ln1_b, xnh);
    gemm_f16<<<dim3(12, 32), 256, 0, stream>>>(xnh, t_saq, sa_bq, sa_bk, sa_bv, nullptr,
        nullptr, nullptr, Qh, Kh, nullptr, Vtb, 2, 1536, 512, 512, 11, 1, 0, 0, QSCALE,
        nullptr, nullptr, nullptr, nullptr, 0);
    attention_split<<<512, 512, 0, stream>>>(Qh, Kh, Vtb, h1h, Lsum, 2048, 2);
    attn_combine<<<8192, 256, 0, stream>>>(h1h, Lsum, ctxh, 4);
    // d) y = xc + xs
    gemm64<<<dim3(8, 64), 256, 0, stream>>>(ctxh, t_sao, sa_bo, XC, Yb, nullptr,
                                            512, 512, 11, 1.0f);
    // e,f) LN2 + GELU MLP
    layernorm_f16<<<4096, 128, 0, stream>>>(Yb, ln2_g, ln2_b, xn2h);
    gemm_f16<<<dim3(16, 32), 256, 0, stream>>>(xn2h, t_w1, mlp_b1, nullptr, nullptr, nullptr,
        nullptr, h1h, nullptr, nullptr, nullptr, nullptr, 0, 2048, 512, 512, 11, 0, 1, 0, 1.0f,
        nullptr, nullptr, nullptr, nullptr, 0);
    // g) out = y + h1 @ w2 + b2: split-K x4 into f32 partials, then combine.
    gemm_f16<<<dim3(4, 32, 4), 256, 0, stream>>>(h1h, t_w2, nullptr, nullptr, nullptr, nullptr,
        Pk, nullptr, nullptr, nullptr, nullptr, nullptr, 0, 512, 512, 2048, 11, 0, 0,
        (size_t)2097152, 1.0f,
        nullptr, nullptr, nullptr, nullptr, 0);
    mlp2_combine<<<2048, 256, 0, stream>>>(Pk, Yb, mlp_b2, out);
}

// Round 13
// 361.095 us; speedup vs baseline: 1.0182x; 1.0182x over previous
//
#include <hip/hip_runtime.h>
#include <math.h>

typedef _Float16 f16;
typedef __attribute__((ext_vector_type(8))) _Float16 f16x8;
typedef __attribute__((ext_vector_type(4))) _Float16 f16x4;
typedef __attribute__((ext_vector_type(4))) float f32x4;
typedef __attribute__((ext_vector_type(16))) float f32x16;
typedef __attribute__((ext_vector_type(2))) __fp16 h16x2;

#define QSCALE 0.1803368801111204f  /* 0.125 * log2(e) */

__device__ __forceinline__ void gl_lds16(const f16* g, f16* l) {
    __builtin_amdgcn_global_load_lds((const __attribute__((address_space(1))) void*)g,
                                     (__attribute__((address_space(3))) void*)l, 16, 0, 0);
}

// ---------------------------------------------------------------------------
// Mega prep kernel: 8 square weight transposes + w1 + w2 transposes + 2 cvts.
// ---------------------------------------------------------------------------
struct PrepArgs {
    const float* ws[10]; f16* wd[10];
    const float* x; f16* xh;
    const float* cross; f16* ch;
};
__global__ __launch_bounds__(256)
void prep_all(PrepArgs p) {
    __shared__ float t[32][33];
    int bid = blockIdx.x, tid = threadIdx.x;
    if (bid < 4096) {
        const float* W; f16* Wt; int K, N, nx, ky;
        if (bid < 2048) {
            int wi = bid >> 8, tl = bid & 255;
            W = p.ws[wi]; Wt = p.wd[wi]; K = 512; N = 512; nx = tl & 15; ky = tl >> 4;
        } else if (bid < 3072) {
            int tl = bid - 2048;
            W = p.ws[8]; Wt = p.wd[8]; K = 512; N = 2048; nx = tl & 63; ky = tl >> 6;
        } else {
            int tl = bid - 3072;
            W = p.ws[9]; Wt = p.wd[9]; K = 2048; N = 512; nx = tl & 15; ky = tl >> 4;
        }
        int tx = tid & 31, ty = tid >> 5;
        int n0 = nx * 32, k0 = ky * 32;
#pragma unroll
        for (int i = 0; i < 4; i++)
            t[ty + i * 8][tx] = W[(size_t)(k0 + ty + i * 8) * N + n0 + tx];
        __syncthreads();
#pragma unroll
        for (int i = 0; i < 4; i++)
            Wt[(size_t)(n0 + ty + i * 8) * K + k0 + tx] = (f16)t[tx][ty + i * 8];
    } else {
        const float* X; f16* Y; size_t cb;
        if (bid < 6144) { X = p.x; Y = p.xh; cb = bid - 4096; }
        else            { X = p.cross; Y = p.ch; cb = bid - 6144; }
        size_t i = (cb * 256 + tid) * 4;
        f32x4 v = *(const f32x4*)(X + i);
        f16x4 o;
        o[0] = (f16)v[0]; o[1] = (f16)v[1]; o[2] = (f16)v[2]; o[3] = (f16)v[3];
        *(f16x4*)(Y + i) = o;
    }
}

// ---------------------------------------------------------------------------
// LayerNorm D=512, f32 in -> f16 out. 1 block (128 thr) per row.
// ---------------------------------------------------------------------------
__global__ __launch_bounds__(128)
void layernorm_f16(const float* __restrict__ X, const float* __restrict__ g,
                   const float* __restrict__ bta, f16* __restrict__ Y)
{
    __shared__ float red[4];
    int row = blockIdx.x;
    int tid = threadIdx.x;
    const float* x = X + (size_t)row * 512;
    f32x4 v = *(const f32x4*)(x + tid * 4);
    float s  = v[0] + v[1] + v[2] + v[3];
    float ss = v[0] * v[0] + v[1] * v[1] + v[2] * v[2] + v[3] * v[3];
#pragma unroll
    for (int m = 1; m < 64; m <<= 1) {
        s  += __shfl_xor(s, m, 64);
        ss += __shfl_xor(ss, m, 64);
    }
    int wave = tid >> 6, lane = tid & 63;
    if (lane == 0) { red[wave * 2] = s; red[wave * 2 + 1] = ss; }
    __syncthreads();
    s = red[0] + red[2]; ss = red[1] + red[3];
    float mu  = s * (1.0f / 512);
    float var = ss * (1.0f / 512) - mu * mu;
    float inv = rsqrtf(var + 1e-5f);
    f32x4 gv = *(const f32x4*)(g + tid * 4);
    f32x4 bv = *(const f32x4*)(bta + tid * 4);
    f16x4 o;
#pragma unroll
    for (int i = 0; i < 4; i++) o[i] = (f16)((v[i] - mu) * inv * gv[i] + bv[i]);
    *(f16x4*)(Y + (size_t)row * 512 + tid * 4) = o;
}

// ---------------------------------------------------------------------------
// GEMM 128x128 tile, BK=64, DOUBLE-BUFFERED LDS, XOR-swizzled rows.
// vtp/vseg: V output segment written TRANSPOSED [bh][64][NB] (fused transpose).
// Kstride: row stride of A/Wt (> K enables K-slicing via blockIdx.z).
// zsl: if nonzero, Cf32 += blockIdx.z * zsl and raw acc is written (split-K
// partials; bias/residual applied later by mlp2_combine).
// ---------------------------------------------------------------------------
__global__ __launch_bounds__(256)
void gemm_f16(const f16* __restrict__ A, const f16* __restrict__ Wt,
              const float* __restrict__ b0, const float* __restrict__ b1,
              const float* __restrict__ b2, const float* __restrict__ res,
              float* __restrict__ Cf32, f16* __restrict__ C16,
              f16* __restrict__ hm0, f16* __restrict__ hm1, f16* __restrict__ hm2,
              f16* __restrict__ vtp, int vseg,
              int N, int K, int Kstride, int NBshift, int fused, int act,
              size_t zsl, float s0)
{
    __shared__ __align__(16) f16 As[2][128 * 64];
    __shared__ __align__(16) f16 Bs[2][128 * 64];
    int tid = threadIdx.x, lane = tid & 63, wave = tid >> 6;
    int quad = lane >> 4, ln16 = lane & 15;
    int wm = wave >> 1, wn = wave & 1;
    int bm0 = blockIdx.y * 128, bn0 = blockIdx.x * 128;
    int kz = blockIdx.z * K;
    if (zsl) Cf32 += blockIdx.z * zsl;

    f32x4 acc[4][4];
#pragma unroll
    for (int i = 0; i < 4; i++)
#pragma unroll
        for (int j = 0; j < 4; j++) acc[i][j] = (f32x4){0.f, 0.f, 0.f, 0.f};

    const f16* ag[4]; const f16* bg[4]; int Loff[4];
#pragma unroll
    for (int j = 0; j < 4; j++) {
        int L = tid + j * 256;
        int row = L >> 3, cc = (L & 7) ^ (row & 7);
        ag[j] = A  + (size_t)(bm0 + row) * Kstride + kz + cc * 8;
        bg[j] = Wt + (size_t)(bn0 + row) * Kstride + kz + cc * 8;
        Loff[j] = L * 8;
    }
    int sw0 = (quad ^ (ln16 & 7)) * 8, sw1 = ((4 + quad) ^ (ln16 & 7)) * 8;

    // prologue
#pragma unroll
    for (int j = 0; j < 4; j++) { gl_lds16(ag[j], &As[0][Loff[j]]); gl_lds16(bg[j], &Bs[0][Loff[j]]); }
#pragma unroll
    for (int j = 0; j < 4; j++) { ag[j] += 64; bg[j] += 64; }

    int cur = 0;
    for (int kt = 0; kt < K; kt += 64) {
        __syncthreads();
        if (kt + 64 < K) {
            int nxt = cur ^ 1;
#pragma unroll
            for (int j = 0; j < 4; j++) { gl_lds16(ag[j], &As[nxt][Loff[j]]); gl_lds16(bg[j], &Bs[nxt][Loff[j]]); }
#pragma unroll
            for (int j = 0; j < 4; j++) { ag[j] += 64; bg[j] += 64; }
        }
        const f16* Ac = As[cur]; const f16* Bc = Bs[cur];
#pragma unroll
        for (int h = 0; h < 2; h++) {
            int sw = h ? sw1 : sw0;
            f16x8 af[4], bf[4];
#pragma unroll
            for (int mt = 0; mt < 4; mt++)
                af[mt] = *(const f16x8*)&Ac[(wm * 64 + mt * 16 + ln16) * 64 + sw];
#pragma unroll
            for (int nt = 0; nt < 4; nt++)
                bf[nt] = *(const f16x8*)&Bc[(wn * 64 + nt * 16 + ln16) * 64 + sw];
#pragma unroll
            for (int mt = 0; mt < 4; mt++)
#pragma unroll
                for (int nt = 0; nt < 4; nt++)
                    acc[mt][nt] = __builtin_amdgcn_mfma_f32_16x16x32_f16(af[mt], bf[nt], acc[mt][nt], 0, 0, 0);
        }
        cur ^= 1;
    }

    int NB = 1 << NBshift;
#pragma unroll
    for (int mt = 0; mt < 4; mt++) {
#pragma unroll
        for (int nt = 0; nt < 4; nt++) {
            int row = bm0 + wm * 64 + mt * 16 + quad * 4;
            int col = bn0 + wn * 64 + nt * 16 + ln16;
            if (zsl) {
#pragma unroll
                for (int i = 0; i < 4; i++)
                    Cf32[(size_t)(row + i) * N + col] = acc[mt][nt][i];
                continue;
            }
            float bv;
            if (fused) {
                int seg = col >> 9;
                const float* bp = seg == 0 ? b0 : (seg == 1 ? b1 : b2);
                bv = bp[col & 511];
            } else bv = b0[col];
            int seg = col >> 9;
            if (vtp && seg == vseg) {
                // V segment: write transposed [bh][64][NB], 4 tokens per store
                int hh = (col >> 6) & 7, d = col & 63;
                int bt = row >> NBshift, rr = row & (NB - 1);
                f16x4 o4;
#pragma unroll
                for (int i = 0; i < 4; i++) o4[i] = (f16)(acc[mt][nt][i] + bv);
                *(f16x4*)&vtp[(((size_t)bt * 8 + hh) * 64 + d) * NB + rr] = o4;
            } else {
#pragma unroll
                for (int i = 0; i < 4; i++) {
                    int r = row + i;
                    float v = acc[mt][nt][i] + bv;
                    size_t idx = (size_t)r * N + col;
                    if (res) v += res[idx];
                    if (act) v = 0.5f * v * (1.0f + erff(v * 0.70710678118654752f));
                    if (Cf32) Cf32[idx] = v;
                    if (C16) C16[idx] = (f16)v;
                    if (hm0) {
                        f16* hp = seg == 0 ? hm0 : (seg == 1 ? hm1 : hm2);
                        float vv = seg == 0 ? v * s0 : v;
                        int hh = (col >> 6) & 7, d = col & 63;
                        int bt = r >> NBshift, rr = r & (NB - 1);
                        hp[(((size_t)bt * 8 + hh) * NB + rr) * 64 + d] = (f16)vv;
                    }
                }
            }
        }
    }
}

// ---------------------------------------------------------------------------
// MLP2 combine: out = Yb + b2 + sum of 4 f32 partial slices.  Pure BW
// (~48 MB).  grid 2048 x 256, 4 f32/thread.
// ---------------------------------------------------------------------------
__global__ __launch_bounds__(256)
void mlp2_combine(const float* __restrict__ Pk, const float* __restrict__ Yb,
                  const float* __restrict__ b2, float* __restrict__ out)
{
    size_t i = ((size_t)blockIdx.x * 256 + threadIdx.x) * 4;
    int col = (int)(i & 511);
    f32x4 v = *(const f32x4*)(Yb + i);
    f32x4 bb = *(const f32x4*)(b2 + col);
#pragma unroll
    for (int s = 0; s < 4; s++) {
        f32x4 p = *(const f32x4*)(Pk + (size_t)s * 2097152 + i);
#pragma unroll
        for (int j = 0; j < 4; j++) v[j] += p[j];
    }
#pragma unroll
    for (int j = 0; j < 4; j++) v[j] += bb[j];
    *(f32x4*)(out + i) = v;
}

// ---------------------------------------------------------------------------
// GEMM 64x64 tile, BK=64, DOUBLE-BUFFERED LDS.  N=512 shapes (512 blocks).
// ---------------------------------------------------------------------------
__global__ __launch_bounds__(256)
void gemm64(const f16* __restrict__ A, const f16* __restrict__ Wt,
            const float* __restrict__ bias, const float* __restrict__ res,
            float* __restrict__ Cf32, f16* __restrict__ hm0,
            int N, int K, int NBshift, float s0)
{
    __shared__ __align__(16) f16 As[2][64 * 64];
    __shared__ __align__(16) f16 Bs[2][64 * 64];
    int tid = threadIdx.x, lane = tid & 63, wave = tid >> 6;
    int quad = lane >> 4, ln16 = lane & 15;
    int wm = wave >> 1, wn = wave & 1;
    int bm0 = blockIdx.y * 64, bn0 = blockIdx.x * 64;

    f32x4 acc[2][2];
#pragma unroll
    for (int i = 0; i < 2; i++)
#pragma unroll
        for (int j = 0; j < 2; j++) acc[i][j] = (f32x4){0.f, 0.f, 0.f, 0.f};

    const f16* ag[2]; const f16* bg[2]; int Loff[2];
#pragma unroll
    for (int j = 0; j < 2; j++) {
        int L = tid + j * 256;
        int row = L >> 3, cc = (L & 7) ^ (row & 7);
        ag[j] = A  + (size_t)(bm0 + row) * K + cc * 8;
        bg[j] = Wt + (size_t)(bn0 + row) * K + cc * 8;
        Loff[j] = L * 8;
    }
    int sw0 = (quad ^ (ln16 & 7)) * 8, sw1 = ((4 + quad) ^ (ln16 & 7)) * 8;

#pragma unroll
    for (int j = 0; j < 2; j++) { gl_lds16(ag[j], &As[0][Loff[j]]); gl_lds16(bg[j], &Bs[0][Loff[j]]); }
#pragma unroll
    for (int j = 0; j < 2; j++) { ag[j] += 64; bg[j] += 64; }

    int cur = 0;
    for (int kt = 0; kt < K; kt += 64) {
        __syncthreads();
        if (kt + 64 < K) {
            int nxt = cur ^ 1;
#pragma unroll
            for (int j = 0; j < 2; j++) { gl_lds16(ag[j], &As[nxt][Loff[j]]); gl_lds16(bg[j], &Bs[nxt][Loff[j]]); }
#pragma unroll
            for (int j = 0; j < 2; j++) { ag[j] += 64; bg[j] += 64; }
        }
        const f16* Ac = As[cur]; const f16* Bc = Bs[cur];
#pragma unroll
        for (int h = 0; h < 2; h++) {
            int sw = h ? sw1 : sw0;
            f16x8 af[2], bf[2];
#pragma unroll
            for (int mt = 0; mt < 2; mt++)
                af[mt] = *(const f16x8*)&Ac[(wm * 32 + mt * 16 + ln16) * 64 + sw];
#pragma unroll
            for (int nt = 0; nt < 2; nt++)
                bf[nt] = *(const f16x8*)&Bc[(wn * 32 + nt * 16 + ln16) * 64 + sw];
#pragma unroll
            for (int mt = 0; mt < 2; mt++)
#pragma unroll
                for (int nt = 0; nt < 2; nt++)
                    acc[mt][nt] = __builtin_amdgcn_mfma_f32_16x16x32_f16(af[mt], bf[nt], acc[mt][nt], 0, 0, 0);
        }
        cur ^= 1;
    }

    int NB = 1 << NBshift;
#pragma unroll
    for (int mt = 0; mt < 2; mt++) {
#pragma unroll
        for (int nt = 0; nt < 2; nt++) {
            int row = bm0 + wm * 32 + mt * 16 + quad * 4;
            int col = bn0 + wn * 32 + nt * 16 + ln16;
            float bv = bias[col];
#pragma unroll
            for (int i = 0; i < 4; i++) {
                int r = row + i;
                float v = acc[mt][nt][i] + bv;
                size_t idx = (size_t)r * N + col;
                if (res) v += res[idx];
                if (Cf32) Cf32[idx] = v;
                if (hm0) {
                    int hh = (col >> 6) & 7, d = col & 63;
                    int bt = r >> NBshift, rr = r & (NB - 1);
                    hm0[(((size_t)bt * 8 + hh) * NB + rr) * 64 + d] = (f16)(v * s0);
                }
            }
        }
    }
}

// ---------------------------------------------------------------------------
// Flash attention v13 (best measured config, r7 = 352.8 us total):
// all-32x32x16 MFMA, raw v_exp_f32, 4-way split l-accumulator, 64-key tiles,
// register-resident P via lane-half exchange.  512 thr = 8 waves, 32 q/wave;
// double-buffered K/V; split-K x4.  NOTE (r5/r6): (512,4) caps arch+acc
// VGPRs at 128 total (v13 = 64+48 = 112); any growth spills (WRITE_SIZE is
// the tripwire).  r8-r11 established: XCD co-location / setprio / P-exchange
// removal / barrier-halving are all time-neutral on this structure -- the
// remaining gap is the 2-phase schedule itself (8-phase rewrite territory).
// ---------------------------------------------------------------------------
__global__ __launch_bounds__(512, 4)
void attention_split(const f16* __restrict__ Qh, const f16* __restrict__ Kh,
                     const f16* __restrict__ Vt, f16* __restrict__ Op,
                     float* __restrict__ Lsum, int Nk, int nsp_log)
{
    __shared__ __align__(16) f16 Kt[2][64 * 64];
    __shared__ __align__(16) f16 Vs[2][64 * 64];
    int z = blockIdx.z, b = z >> nsp_log, sp = z & ((1 << nsp_log) - 1);
    int h8 = blockIdx.y, bh = b * 8 + h8;
    int Nkh = Nk >> nsp_log;
    int tid = threadIdx.x, lane = tid & 63, wave = tid >> 6;
    int lq = lane & 31, hh = lane >> 5, l7 = lane & 7;
    int qrow0 = blockIdx.x * 256 + wave * 32;

    // Q B-frags (32x32x16): lane holds q = qrow0+lq, d = s*16 + hh*8 + (0..7)
    f16x8 qf[4];
#pragma unroll
    for (int s = 0; s < 4; s++)
        qf[s] = *(const f16x8*)(Qh + ((size_t)bh * 2048 + qrow0 + lq) * 64 + s * 16 + hh * 8);

    f32x16 oacc[2];
#pragma unroll
    for (int db = 0; db < 2; db++)
#pragma unroll
        for (int r = 0; r < 16; r++) oacc[db][r] = 0.f;
    float la[4] = {0.f, 0.f, 0.f, 0.f};

    const f16* kb = Kh + ((size_t)bh * Nk + sp * Nkh) * 64;
    const f16* vb = Vt + (size_t)bh * 64 * Nk + sp * Nkh;

    const f16* kg; const f16* vg; int Lo;
    {
        int L = tid;
        int row = L >> 3, cc = (L & 7) ^ (row & 7);
        kg = kb + (size_t)row * 64 + cc * 8;
        vg = vb + (size_t)row * Nk + cc * 8;
        Lo = L * 8;
    }

    // LDS read offsets (f16 units), shared by K (g=key-half, s=d-step) and
    // V (g=d-half, s=key-step): row = g*32+lq, chunk = (2s+hh)^(row&7)
    int off[2][4];
#pragma unroll
    for (int g = 0; g < 2; g++)
#pragma unroll
        for (int s = 0; s < 4; s++)
            off[g][s] = (g * 32 + lq) * 64 + (((2 * s + hh) ^ l7) * 8);

    // prologue: tile 0 -> buf 0
    gl_lds16(kg, &Kt[0][Lo]);
    gl_lds16(vg, &Vs[0][Lo]);
    kg += 64 * 64; vg += 64;

    int cur = 0;
    for (int kt = 0; kt < Nkh; kt += 64) {
        __syncthreads();
        if (kt + 64 < Nkh) {
            int nxt = cur ^ 1;
            gl_lds16(kg, &Kt[nxt][Lo]);
            gl_lds16(vg, &Vs[nxt][Lo]);
            kg += 64 * 64; vg += 64;
        }
        const f16* Ktc = Kt[cur]; const f16* Vsc = Vs[cur];

#pragma unroll
        for (int kbk = 0; kbk < 2; kbk++) {
            // ---- QK^T for 32 keys: S^T C-layout, key = kbk*32+(r&3)+8*(r>>2)+4hh
            f32x16 c;
#pragma unroll
            for (int r = 0; r < 16; r++) c[r] = 0.f;
#pragma unroll
            for (int s = 0; s < 4; s++) {
                f16x8 kf = *(const f16x8*)&Ktc[off[kbk][s]];
                c = __builtin_amdgcn_mfma_f32_32x32x16_f16(kf, qf[s], c, 0, 0, 0);
            }
            // ---- exp2 + l-accumulate + pack pairs
            int pr[8];
#pragma unroll
            for (int m = 0; m < 8; m++) {
                float e0 = __builtin_amdgcn_exp2f(c[2 * m]);
                float e1 = __builtin_amdgcn_exp2f(c[2 * m + 1]);
                la[2 * (m & 1)]     += e0;
                la[2 * (m & 1) + 1] += e1;
                union { h16x2 h; int i; } u;
                u.h = __builtin_amdgcn_cvt_pkrtz(e0, e1);
                pr[m] = u.i;
            }
            // pr[m]@hh holds keys (local): m0:{4hh,4hh+1} m1:{4hh+2,4hh+3}
            // m2:{8+4hh,..} m3:{10+4hh,..} m4..7: +16 of m0..3
#pragma unroll
            for (int t = 0; t < 2; t++) {
                int p0 = pr[4 * t + 0], p1 = pr[4 * t + 1];
                int p2 = pr[4 * t + 2], p3 = pr[4 * t + 3];
                int s0 = __shfl_xor(p0, 32, 64);
                int s1 = __shfl_xor(p1, 32, 64);
                int s2 = __shfl_xor(p2, 32, 64);
                int s3 = __shfl_xor(p3, 32, 64);
                union { int i[4]; f16x8 v; } bu;
                bu.i[0] = hh ? s2 : p0;   // keys hh*8 + {0,1}
                bu.i[1] = hh ? s3 : p1;   // keys hh*8 + {2,3}
                bu.i[2] = hh ? p2 : s0;   // keys hh*8 + {4,5}
                bu.i[3] = hh ? p3 : s1;   // keys hh*8 + {6,7}
                int ks = kbk * 2 + t;
#pragma unroll
                for (int db = 0; db < 2; db++) {
                    f16x8 vf = *(const f16x8*)&Vsc[off[db][ks]];
                    oacc[db] = __builtin_amdgcn_mfma_f32_32x32x16_f16(vf, bu.v, oacc[db], 0, 0, 0);
                }
            }
        }
        cur ^= 1;
    }

    // epilogue: lane holds q = qrow0+lq; oacc[db][r] -> d = db*32+(r&3)+8*(r>>2)+4hh
    float lacc = (la[0] + la[1]) + (la[2] + la[3]);
    float ltot = lacc + __shfl_xor(lacc, 32, 64);
    size_t rowb = ((size_t)(sp * 16 + bh) * 2048 + qrow0 + lq) * 64;
#pragma unroll
    for (int db = 0; db < 2; db++)
#pragma unroll
        for (int rq = 0; rq < 4; rq++) {
            f16x4 o4;
#pragma unroll
            for (int i = 0; i < 4; i++) o4[i] = (f16)oacc[db][rq * 4 + i];
            *(f16x4*)&Op[rowb + db * 32 + rq * 8 + hh * 4] = o4;
        }
    if (hh == 0)
        Lsum[(size_t)(sp * 16 + bh) * 2048 + qrow0 + lq] = ltot;
}

// ---------------------------------------------------------------------------
// Combine nsplit key-splits (shared implicit max -> plain sums). grid 8192x256.
// ---------------------------------------------------------------------------
__global__ __launch_bounds__(256)
void attn_combine(const f16* __restrict__ Op, const float* __restrict__ Lsum,
                  f16* __restrict__ O, int nsplit)
{
    int t = blockIdx.x * 256 + threadIdx.x;
    int d = t & 63;
    int q = (t >> 6) & 2047;
    int bh = t >> 17;
    int b = bh >> 3, h = bh & 7;
    float l = 0.f, val = 0.f;
#pragma unroll 4
    for (int s = 0; s < nsplit; s++) {
        l   += Lsum[(size_t)(s * 16 + bh) * 2048 + q];
        val += (float)Op[((size_t)(s * 16 + bh) * 2048 + q) * 64 + d];
    }
    O[((size_t)b * 2048 + q) * 512 + h * 64 + d] = (f16)(val / l);
}

// ---------------------------------------------------------------------------
extern "C" void kernel_launch(void* const* d_in, const int* in_sizes, int n_in,
                              void* d_out, int out_size, void* d_ws, size_t ws_size,
                              hipStream_t stream)
{
    (void)in_sizes; (void)n_in; (void)out_size; (void)ws_size;
    const float* x      = (const float*)d_in[0];
    const float* cross  = (const float*)d_in[1];
    const float* ca_wq  = (const float*)d_in[2];
    const float* ca_bq  = (const float*)d_in[3];
    const float* ca_wk  = (const float*)d_in[4];
    const float* ca_bk  = (const float*)d_in[5];
    const float* ca_wv  = (const float*)d_in[6];
    const float* ca_bv  = (const float*)d_in[7];
    const float* ca_wo  = (const float*)d_in[8];
    const float* ca_bo  = (const float*)d_in[9];
    const float* sa_wq  = (const float*)d_in[10];
    const float* sa_bq  = (const float*)d_in[11];
    const float* sa_wk  = (const float*)d_in[12];
    const float* sa_bk  = (const float*)d_in[13];
    const float* sa_wv  = (const float*)d_in[14];
    const float* sa_bv  = (const float*)d_in[15];
    const float* sa_wo  = (const float*)d_in[16];
    const float* sa_bo  = (const float*)d_in[17];
    const float* ln1_g  = (const float*)d_in[18];
    const float* ln1_b  = (const float*)d_in[19];
    const float* ln2_g  = (const float*)d_in[20];
    const float* ln2_b  = (const float*)d_in[21];
    const float* mlp_w1 = (const float*)d_in[22];
    const float* mlp_b1 = (const float*)d_in[23];
    const float* mlp_w2 = (const float*)d_in[24];
    const float* mlp_b2 = (const float*)d_in[25];
    float* out = (float*)d_out;

    // ---- workspace layout ----
    float* XC = (float*)d_ws;            // 2M f32
    float* Yb = XC + 2097152;            // 2M f32
    f16* fb   = (f16*)(Yb + 2097152);
    f16* xh     = fb;                    // 2M
    f16* crossh = xh + 2097152;          // 4M
    f16* xnh    = crossh + 4194304;      // 2M
    f16* xn2h   = xnh + 2097152;         // 2M
    f16* Qh     = xn2h + 2097152;        // 2M
    f16* Kh     = Qh + 2097152;          // 4M
    f16* Vh     = Kh + 4194304;          // 4M (unused; kept for layout stability)
    f16* Vtb    = Vh + 4194304;          // 4M
    f16* ctxh   = Vtb + 4194304;         // 2M
    f16* h1h    = ctxh + 2097152;        // 8M (reused as attention partials Op)
    f16* t_caq  = h1h + 8388608;
    f16* t_cak  = t_caq + 262144;
    f16* t_cav  = t_cak + 262144;
    f16* t_cao  = t_cav + 262144;
    f16* t_saq  = t_cao + 262144;
    f16* t_sak  = t_saq + 262144;
    f16* t_sav  = t_sak + 262144;
    f16* t_sao  = t_sav + 262144;
    f16* t_w1   = t_sao + 262144;        // 1M
    f16* t_w2   = t_w1 + 1048576;        // 1M
    float* Lsum = (float*)(t_w2 + 1048576);   // 131072 floats

    // MLP2 split-K partials: 4 x [4096][512] f32 = 32 MB, aliasing the dead
    // Qh..ctxh region (Qh/Kh/Vh/Vtb dead after self-attn; ctxh dead after
    // step d, which precedes MLP2).
    float* Pk = (float*)Qh;

    PrepArgs pa;
    pa.ws[0] = ca_wq; pa.wd[0] = t_caq;
    pa.ws[1] = ca_wk; pa.wd[1] = t_cak;
    pa.ws[2] = ca_wv; pa.wd[2] = t_cav;
    pa.ws[3] = ca_wo; pa.wd[3] = t_cao;
    pa.ws[4] = sa_wq; pa.wd[4] = t_saq;
    pa.ws[5] = sa_wk; pa.wd[5] = t_sak;
    pa.ws[6] = sa_wv; pa.wd[6] = t_sav;
    pa.ws[7] = sa_wo; pa.wd[7] = t_sao;
    pa.ws[8] = mlp_w1; pa.wd[8] = t_w1;
    pa.ws[9] = mlp_w2; pa.wd[9] = t_w2;
    pa.x = x; pa.xh = xh; pa.cross = cross; pa.ch = crossh;
    prep_all<<<10240, 256, 0, stream>>>(pa);

    // a) cross-attention (split-K x4; V written pre-transposed by the gemm)
    gemm64<<<dim3(8, 64), 256, 0, stream>>>(xh, t_caq, ca_bq, nullptr, nullptr, Qh,
                                            512, 512, 11, QSCALE);
    gemm_f16<<<dim3(8, 64), 256, 0, stream>>>(crossh, t_cak, ca_bk, ca_bv, nullptr, nullptr,
        nullptr, nullptr, Kh, nullptr, nullptr, Vtb, 1, 1024, 512, 512, 12, 1, 0, 0, 1.0f);
    attention_split<<<dim3(8, 8, 8), 512, 0, stream>>>(Qh, Kh, Vtb, h1h, Lsum, 4096, 2);
    attn_combine<<<8192, 256, 0, stream>>>(h1h, Lsum, ctxh, 4);
    gemm64<<<dim3(8, 64), 256, 0, stream>>>(ctxh, t_cao, ca_bo, nullptr, XC, nullptr,
                                            512, 512, 11, 1.0f);
    // b,c) LN1 + self-attention (fused QKV, Q pre-scaled; split-K x4)
    layernorm_f16<<<4096, 128, 0, stream>>>(XC, ln1_g, ln1_b, xnh);
    gemm_f16<<<dim3(12, 32), 256, 0, stream>>>(xnh, t_saq, sa_bq, sa_bk, sa_bv, nullptr,
        nullptr, nullptr, Qh, Kh, nullptr, Vtb, 2, 1536, 512, 512, 11, 1, 0, 0, QSCALE);
    attention_split<<<dim3(8, 8, 8), 512, 0, stream>>>(Qh, Kh, Vtb, h1h, Lsum, 2048, 2);
    attn_combine<<<8192, 256, 0, stream>>>(h1h, Lsum, ctxh, 4);
    // d) y = xc + xs
    gemm64<<<dim3(8, 64), 256, 0, stream>>>(ctxh, t_sao, sa_bo, XC, Yb, nullptr,
                                            512, 512, 11, 1.0f);
    // e,f) LN2 + GELU MLP
    layernorm_f16<<<4096, 128, 0, stream>>>(Yb, ln2_g, ln2_b, xn2h);
    gemm_f16<<<dim3(16, 32), 256, 0, stream>>>(xn2h, t_w1, mlp_b1, nullptr, nullptr, nullptr,
        nullptr, h1h, nullptr, nullptr, nullptr, nullptr, 0, 2048, 512, 512, 11, 0, 1, 0, 1.0f);
    // g) out = y + h1 @ w2 + b2: split-K x4 into f32 partials, then combine.
    gemm_f16<<<dim3(4, 32, 4), 256, 0, stream>>>(h1h, t_w2, nullptr, nullptr, nullptr, nullptr,
        Pk, nullptr, nullptr, nullptr, nullptr, nullptr, 0, 512, 512, 2048, 11, 0, 0,
        (size_t)2097152, 1.0f);
    mlp2_combine<<<2048, 256, 0, stream>>>(Pk, Yb, mlp_b2, out);
}

// Round 14
// 352.183 us; speedup vs baseline: 1.0440x; 1.0253x over previous
//
#include <hip/hip_runtime.h>
#include <math.h>

typedef _Float16 f16;
typedef __attribute__((ext_vector_type(8))) _Float16 f16x8;
typedef __attribute__((ext_vector_type(4))) _Float16 f16x4;
typedef __attribute__((ext_vector_type(4))) float f32x4;
typedef __attribute__((ext_vector_type(16))) float f32x16;
typedef __attribute__((ext_vector_type(2))) __fp16 h16x2;

#define QSCALE 0.1803368801111204f  /* 0.125 * log2(e) */

__device__ __forceinline__ void gl_lds16(const f16* g, f16* l) {
    __builtin_amdgcn_global_load_lds((const __attribute__((address_space(1))) void*)g,
                                     (__attribute__((address_space(3))) void*)l, 16, 0, 0);
}

// Fast exact-GELU: erf via Abramowitz-Stegun 7.1.26 (|err| < 1.5e-7, far
// below the f16 output quantum 2^-8).  ~13 branch-free VALU ops using raw
// v_rcp/v_exp vs libm erff's ~25-35 -- the MLP1 epilogue runs this 8.4M
// times and its VALU tail rivals the MFMA phase of that dispatch.
__device__ __forceinline__ float gelu_f(float v) {
    float z = v * 0.70710678118654752f;
    float ax = fabsf(z);
    float t = __builtin_amdgcn_rcpf(1.0f + 0.3275911f * ax);
    float poly = ((((1.061405429f * t - 1.453152027f) * t + 1.421413741f) * t
                   - 0.284496736f) * t + 0.254829592f) * t;
    float e = __builtin_amdgcn_exp2f(-1.4426950408889634f * ax * ax);
    float er = 1.0f - poly * e;
    er = z < 0.f ? -er : er;
    return 0.5f * v * (1.0f + er);
}

// ---------------------------------------------------------------------------
// Mega prep kernel: 8 square weight transposes + w1 + w2 transposes + 2 cvts.
// ---------------------------------------------------------------------------
struct PrepArgs {
    const float* ws[10]; f16* wd[10];
    const float* x; f16* xh;
    const float* cross; f16* ch;
};
__global__ __launch_bounds__(256)
void prep_all(PrepArgs p) {
    __shared__ float t[32][33];
    int bid = blockIdx.x, tid = threadIdx.x;
    if (bid < 4096) {
        const float* W; f16* Wt; int K, N, nx, ky;
        if (bid < 2048) {
            int wi = bid >> 8, tl = bid & 255;
            W = p.ws[wi]; Wt = p.wd[wi]; K = 512; N = 512; nx = tl & 15; ky = tl >> 4;
        } else if (bid < 3072) {
            int tl = bid - 2048;
            W = p.ws[8]; Wt = p.wd[8]; K = 512; N = 2048; nx = tl & 63; ky = tl >> 6;
        } else {
            int tl = bid - 3072;
            W = p.ws[9]; Wt = p.wd[9]; K = 2048; N = 512; nx = tl & 15; ky = tl >> 4;
        }
        int tx = tid & 31, ty = tid >> 5;
        int n0 = nx * 32, k0 = ky * 32;
#pragma unroll
        for (int i = 0; i < 4; i++)
            t[ty + i * 8][tx] = W[(size_t)(k0 + ty + i * 8) * N + n0 + tx];
        __syncthreads();
#pragma unroll
        for (int i = 0; i < 4; i++)
            Wt[(size_t)(n0 + ty + i * 8) * K + k0 + tx] = (f16)t[tx][ty + i * 8];
    } else {
        const float* X; f16* Y; size_t cb;
        if (bid < 6144) { X = p.x; Y = p.xh; cb = bid - 4096; }
        else            { X = p.cross; Y = p.ch; cb = bid - 6144; }
        size_t i = (cb * 256 + tid) * 4;
        f32x4 v = *(const f32x4*)(X + i);
        f16x4 o;
        o[0] = (f16)v[0]; o[1] = (f16)v[1]; o[2] = (f16)v[2]; o[3] = (f16)v[3];
        *(f16x4*)(Y + i) = o;
    }
}

// ---------------------------------------------------------------------------
// LayerNorm D=512, f32 in -> f16 out. 1 block (128 thr) per row.
// ---------------------------------------------------------------------------
__global__ __launch_bounds__(128)
void layernorm_f16(const float* __restrict__ X, const float* __restrict__ g,
                   const float* __restrict__ bta, f16* __restrict__ Y)
{
    __shared__ float red[4];
    int row = blockIdx.x;
    int tid = threadIdx.x;
    const float* x = X + (size_t)row * 512;
    f32x4 v = *(const f32x4*)(x + tid * 4);
    float s  = v[0] + v[1] + v[2] + v[3];
    float ss = v[0] * v[0] + v[1] * v[1] + v[2] * v[2] + v[3] * v[3];
#pragma unroll
    for (int m = 1; m < 64; m <<= 1) {
        s  += __shfl_xor(s, m, 64);
        ss += __shfl_xor(ss, m, 64);
    }
    int wave = tid >> 6, lane = tid & 63;
    if (lane == 0) { red[wave * 2] = s; red[wave * 2 + 1] = ss; }
    __syncthreads();
    s = red[0] + red[2]; ss = red[1] + red[3];
    float mu  = s * (1.0f / 512);
    float var = ss * (1.0f / 512) - mu * mu;
    float inv = rsqrtf(var + 1e-5f);
    f32x4 gv = *(const f32x4*)(g + tid * 4);
    f32x4 bv = *(const f32x4*)(bta + tid * 4);
    f16x4 o;
#pragma unroll
    for (int i = 0; i < 4; i++) o[i] = (f16)((v[i] - mu) * inv * gv[i] + bv[i]);
    *(f16x4*)(Y + (size_t)row * 512 + tid * 4) = o;
}

// ---------------------------------------------------------------------------
// GEMM 128x128 tile, BK=64, DOUBLE-BUFFERED LDS, XOR-swizzled rows.
// vtp/vseg: V output segment written TRANSPOSED [bh][64][NB] (fused transpose).
// Kstride: row stride of A/Wt (> K enables K-slicing via blockIdx.z).
// zsl: if nonzero, Cf32 += blockIdx.z * zsl and raw acc is written (split-K
// partials; bias/residual applied later by mlp2_combine).
// ---------------------------------------------------------------------------
__global__ __launch_bounds__(256)
void gemm_f16(const f16* __restrict__ A, const f16* __restrict__ Wt,
              const float* __restrict__ b0, const float* __restrict__ b1,
              const float* __restrict__ b2, const float* __restrict__ res,
              float* __restrict__ Cf32, f16* __restrict__ C16,
              f16* __restrict__ hm0, f16* __restrict__ hm1, f16* __restrict__ hm2,
              f16* __restrict__ vtp, int vseg,
              int N, int K, int Kstride, int NBshift, int fused, int act,
              size_t zsl, float s0)
{
    __shared__ __align__(16) f16 As[2][128 * 64];
    __shared__ __align__(16) f16 Bs[2][128 * 64];
    int tid = threadIdx.x, lane = tid & 63, wave = tid >> 6;
    int quad = lane >> 4, ln16 = lane & 15;
    int wm = wave >> 1, wn = wave & 1;
    int bm0 = blockIdx.y * 128, bn0 = blockIdx.x * 128;
    int kz = blockIdx.z * K;
    if (zsl) Cf32 += blockIdx.z * zsl;

    f32x4 acc[4][4];
#pragma unroll
    for (int i = 0; i < 4; i++)
#pragma unroll
        for (int j = 0; j < 4; j++) acc[i][j] = (f32x4){0.f, 0.f, 0.f, 0.f};

    const f16* ag[4]; const f16* bg[4]; int Loff[4];
#pragma unroll
    for (int j = 0; j < 4; j++) {
        int L = tid + j * 256;
        int row = L >> 3, cc = (L & 7) ^ (row & 7);
        ag[j] = A  + (size_t)(bm0 + row) * Kstride + kz + cc * 8;
        bg[j] = Wt + (size_t)(bn0 + row) * Kstride + kz + cc * 8;
        Loff[j] = L * 8;
    }
    int sw0 = (quad ^ (ln16 & 7)) * 8, sw1 = ((4 + quad) ^ (ln16 & 7)) * 8;

    // prologue
#pragma unroll
    for (int j = 0; j < 4; j++) { gl_lds16(ag[j], &As[0][Loff[j]]); gl_lds16(bg[j], &Bs[0][Loff[j]]); }
#pragma unroll
    for (int j = 0; j < 4; j++) { ag[j] += 64; bg[j] += 64; }

    int cur = 0;
    for (int kt = 0; kt < K; kt += 64) {
        __syncthreads();
        if (kt + 64 < K) {
            int nxt = cur ^ 1;
#pragma unroll
            for (int j = 0; j < 4; j++) { gl_lds16(ag[j], &As[nxt][Loff[j]]); gl_lds16(bg[j], &Bs[nxt][Loff[j]]); }
#pragma unroll
            for (int j = 0; j < 4; j++) { ag[j] += 64; bg[j] += 64; }
        }
        const f16* Ac = As[cur]; const f16* Bc = Bs[cur];
#pragma unroll
        for (int h = 0; h < 2; h++) {
            int sw = h ? sw1 : sw0;
            f16x8 af[4], bf[4];
#pragma unroll
            for (int mt = 0; mt < 4; mt++)
                af[mt] = *(const f16x8*)&Ac[(wm * 64 + mt * 16 + ln16) * 64 + sw];
#pragma unroll
            for (int nt = 0; nt < 4; nt++)
                bf[nt] = *(const f16x8*)&Bc[(wn * 64 + nt * 16 + ln16) * 64 + sw];
#pragma unroll
            for (int mt = 0; mt < 4; mt++)
#pragma unroll
                for (int nt = 0; nt < 4; nt++)
                    acc[mt][nt] = __builtin_amdgcn_mfma_f32_16x16x32_f16(af[mt], bf[nt], acc[mt][nt], 0, 0, 0);
        }
        cur ^= 1;
    }

    int NB = 1 << NBshift;
#pragma unroll
    for (int mt = 0; mt < 4; mt++) {
#pragma unroll
        for (int nt = 0; nt < 4; nt++) {
            int row = bm0 + wm * 64 + mt * 16 + quad * 4;
            int col = bn0 + wn * 64 + nt * 16 + ln16;
            if (zsl) {
#pragma unroll
                for (int i = 0; i < 4; i++)
                    Cf32[(size_t)(row + i) * N + col] = acc[mt][nt][i];
                continue;
            }
            float bv;
            if (fused) {
                int seg = col >> 9;
                const float* bp = seg == 0 ? b0 : (seg == 1 ? b1 : b2);
                bv = bp[col & 511];
            } else bv = b0[col];
            int seg = col >> 9;
            if (vtp && seg == vseg) {
                // V segment: write transposed [bh][64][NB], 4 tokens per store
                int hh = (col >> 6) & 7, d = col & 63;
                int bt = row >> NBshift, rr = row & (NB - 1);
                f16x4 o4;
#pragma unroll
                for (int i = 0; i < 4; i++) o4[i] = (f16)(acc[mt][nt][i] + bv);
                *(f16x4*)&vtp[(((size_t)bt * 8 + hh) * 64 + d) * NB + rr] = o4;
            } else {
#pragma unroll
                for (int i = 0; i < 4; i++) {
                    int r = row + i;
                    float v = acc[mt][nt][i] + bv;
                    size_t idx = (size_t)r * N + col;
                    if (res) v += res[idx];
                    if (act) v = gelu_f(v);
                    if (Cf32) Cf32[idx] = v;
                    if (C16) C16[idx] = (f16)v;
                    if (hm0) {
                        f16* hp = seg == 0 ? hm0 : (seg == 1 ? hm1 : hm2);
                        float vv = seg == 0 ? v * s0 : v;
                        int hh = (col >> 6) & 7, d = col & 63;
                        int bt = r >> NBshift, rr = r & (NB - 1);
                        hp[(((size_t)bt * 8 + hh) * NB + rr) * 64 + d] = (f16)vv;
                    }
                }
            }
        }
    }
}

// ---------------------------------------------------------------------------
// MLP2 combine: out = Yb + b2 + sum of 4 f32 partial slices.  Pure BW
// (~48 MB).  grid 2048 x 256, 4 f32/thread.
// ---------------------------------------------------------------------------
__global__ __launch_bounds__(256)
void mlp2_combine(const float* __restrict__ Pk, const float* __restrict__ Yb,
                  const float* __restrict__ b2, float* __restrict__ out)
{
    size_t i = ((size_t)blockIdx.x * 256 + threadIdx.x) * 4;
    int col = (int)(i & 511);
    f32x4 v = *(const f32x4*)(Yb + i);
    f32x4 bb = *(const f32x4*)(b2 + col);
#pragma unroll
    for (int s = 0; s < 4; s++) {
        f32x4 p = *(const f32x4*)(Pk + (size_t)s * 2097152 + i);
#pragma unroll
        for (int j = 0; j < 4; j++) v[j] += p[j];
    }
#pragma unroll
    for (int j = 0; j < 4; j++) v[j] += bb[j];
    *(f32x4*)(out + i) = v;
}

// ---------------------------------------------------------------------------
// GEMM 64x64 tile, BK=64, DOUBLE-BUFFERED LDS.  N=512 shapes (512 blocks).
// ---------------------------------------------------------------------------
__global__ __launch_bounds__(256)
void gemm64(const f16* __restrict__ A, const f16* __restrict__ Wt,
            const float* __restrict__ bias, const float* __restrict__ res,
            float* __restrict__ Cf32, f16* __restrict__ hm0,
            int N, int K, int NBshift, float s0)
{
    __shared__ __align__(16) f16 As[2][64 * 64];
    __shared__ __align__(16) f16 Bs[2][64 * 64];
    int tid = threadIdx.x, lane = tid & 63, wave = tid >> 6;
    int quad = lane >> 4, ln16 = lane & 15;
    int wm = wave >> 1, wn = wave & 1;
    int bm0 = blockIdx.y * 64, bn0 = blockIdx.x * 64;

    f32x4 acc[2][2];
#pragma unroll
    for (int i = 0; i < 2; i++)
#pragma unroll
        for (int j = 0; j < 2; j++) acc[i][j] = (f32x4){0.f, 0.f, 0.f, 0.f};

    const f16* ag[2]; const f16* bg[2]; int Loff[2];
#pragma unroll
    for (int j = 0; j < 2; j++) {
        int L = tid + j * 256;
        int row = L >> 3, cc = (L & 7) ^ (row & 7);
        ag[j] = A  + (size_t)(bm0 + row) * K + cc * 8;
        bg[j] = Wt + (size_t)(bn0 + row) * K + cc * 8;
        Loff[j] = L * 8;
    }
    int sw0 = (quad ^ (ln16 & 7)) * 8, sw1 = ((4 + quad) ^ (ln16 & 7)) * 8;

#pragma unroll
    for (int j = 0; j < 2; j++) { gl_lds16(ag[j], &As[0][Loff[j]]); gl_lds16(bg[j], &Bs[0][Loff[j]]); }
#pragma unroll
    for (int j = 0; j < 2; j++) { ag[j] += 64; bg[j] += 64; }

    int cur = 0;
    for (int kt = 0; kt < K; kt += 64) {
        __syncthreads();
        if (kt + 64 < K) {
            int nxt = cur ^ 1;
#pragma unroll
            for (int j = 0; j < 2; j++) { gl_lds16(ag[j], &As[nxt][Loff[j]]); gl_lds16(bg[j], &Bs[nxt][Loff[j]]); }
#pragma unroll
            for (int j = 0; j < 2; j++) { ag[j] += 64; bg[j] += 64; }
        }
        const f16* Ac = As[cur]; const f16* Bc = Bs[cur];
#pragma unroll
        for (int h = 0; h < 2; h++) {
            int sw = h ? sw1 : sw0;
            f16x8 af[2], bf[2];
#pragma unroll
            for (int mt = 0; mt < 2; mt++)
                af[mt] = *(const f16x8*)&Ac[(wm * 32 + mt * 16 + ln16) * 64 + sw];
#pragma unroll
            for (int nt = 0; nt < 2; nt++)
                bf[nt] = *(const f16x8*)&Bc[(wn * 32 + nt * 16 + ln16) * 64 + sw];
#pragma unroll
            for (int mt = 0; mt < 2; mt++)
#pragma unroll
                for (int nt = 0; nt < 2; nt++)
                    acc[mt][nt] = __builtin_amdgcn_mfma_f32_16x16x32_f16(af[mt], bf[nt], acc[mt][nt], 0, 0, 0);
        }
        cur ^= 1;
    }

    int NB = 1 << NBshift;
#pragma unroll
    for (int mt = 0; mt < 2; mt++) {
#pragma unroll
        for (int nt = 0; nt < 2; nt++) {
            int row = bm0 + wm * 32 + mt * 16 + quad * 4;
            int col = bn0 + wn * 32 + nt * 16 + ln16;
            float bv = bias[col];
#pragma unroll
            for (int i = 0; i < 4; i++) {
                int r = row + i;
                float v = acc[mt][nt][i] + bv;
                size_t idx = (size_t)r * N + col;
                if (res) v += res[idx];
                if (Cf32) Cf32[idx] = v;
                if (hm0) {
                    int hh = (col >> 6) & 7, d = col & 63;
                    int bt = r >> NBshift, rr = r & (NB - 1);
                    hm0[(((size_t)bt * 8 + hh) * NB + rr) * 64 + d] = (f16)(v * s0);
                }
            }
        }
    }
}

// ---------------------------------------------------------------------------
// Flash attention v13 (best measured config; r7=352.8 / r13=361.1, noise +-8):
// all-32x32x16 MFMA, raw v_exp_f32, 4-way split l-accumulator, 64-key tiles,
// register-resident P via lane-half exchange.  512 thr = 8 waves, 32 q/wave;
// double-buffered K/V; split-K x4.  NOTE (r5/r6): (512,4) caps arch+acc
// VGPRs at 128 total (v13 = 64+48 = 112); any growth spills (WRITE_SIZE is
// the tripwire).  r8-r11 established: XCD co-location / setprio / P-exchange
// removal / barrier-halving are all time-neutral on this structure -- the
// remaining gap is the 2-phase schedule itself (8-phase rewrite territory).
// ---------------------------------------------------------------------------
__global__ __launch_bounds__(512, 4)
void attention_split(const f16* __restrict__ Qh, const f16* __restrict__ Kh,
                     const f16* __restrict__ Vt, f16* __restrict__ Op,
                     float* __restrict__ Lsum, int Nk, int nsp_log)
{
    __shared__ __align__(16) f16 Kt[2][64 * 64];
    __shared__ __align__(16) f16 Vs[2][64 * 64];
    int z = blockIdx.z, b = z >> nsp_log, sp = z & ((1 << nsp_log) - 1);
    int h8 = blockIdx.y, bh = b * 8 + h8;
    int Nkh = Nk >> nsp_log;
    int tid = threadIdx.x, lane = tid & 63, wave = tid >> 6;
    int lq = lane & 31, hh = lane >> 5, l7 = lane & 7;
    int qrow0 = blockIdx.x * 256 + wave * 32;

    // Q B-frags (32x32x16): lane holds q = qrow0+lq, d = s*16 + hh*8 + (0..7)
    f16x8 qf[4];
#pragma unroll
    for (int s = 0; s < 4; s++)
        qf[s] = *(const f16x8*)(Qh + ((size_t)bh * 2048 + qrow0 + lq) * 64 + s * 16 + hh * 8);

    f32x16 oacc[2];
#pragma unroll
    for (int db = 0; db < 2; db++)
#pragma unroll
        for (int r = 0; r < 16; r++) oacc[db][r] = 0.f;
    float la[4] = {0.f, 0.f, 0.f, 0.f};

    const f16* kb = Kh + ((size_t)bh * Nk + sp * Nkh) * 64;
    const f16* vb = Vt + (size_t)bh * 64 * Nk + sp * Nkh;

    const f16* kg; const f16* vg; int Lo;
    {
        int L = tid;
        int row = L >> 3, cc = (L & 7) ^ (row & 7);
        kg = kb + (size_t)row * 64 + cc * 8;
        vg = vb + (size_t)row * Nk + cc * 8;
        Lo = L * 8;
    }

    // LDS read offsets (f16 units), shared by K (g=key-half, s=d-step) and
    // V (g=d-half, s=key-step): row = g*32+lq, chunk = (2s+hh)^(row&7)
    int off[2][4];
#pragma unroll
    for (int g = 0; g < 2; g++)
#pragma unroll
        for (int s = 0; s < 4; s++)
            off[g][s] = (g * 32 + lq) * 64 + (((2 * s + hh) ^ l7) * 8);

    // prologue: tile 0 -> buf 0
    gl_lds16(kg, &Kt[0][Lo]);
    gl_lds16(vg, &Vs[0][Lo]);
    kg += 64 * 64; vg += 64;

    int cur = 0;
    for (int kt = 0; kt < Nkh; kt += 64) {
        __syncthreads();
        if (kt + 64 < Nkh) {
            int nxt = cur ^ 1;
            gl_lds16(kg, &Kt[nxt][Lo]);
            gl_lds16(vg, &Vs[nxt][Lo]);
            kg += 64 * 64; vg += 64;
        }
        const f16* Ktc = Kt[cur]; const f16* Vsc = Vs[cur];

#pragma unroll
        for (int kbk = 0; kbk < 2; kbk++) {
            // ---- QK^T for 32 keys: S^T C-layout, key = kbk*32+(r&3)+8*(r>>2)+4hh
            f32x16 c;
#pragma unroll
            for (int r = 0; r < 16; r++) c[r] = 0.f;
#pragma unroll
            for (int s = 0; s < 4; s++) {
                f16x8 kf = *(const f16x8*)&Ktc[off[kbk][s]];
                c = __builtin_amdgcn_mfma_f32_32x32x16_f16(kf, qf[s], c, 0, 0, 0);
            }
            // ---- exp2 + l-accumulate + pack pairs
            int pr[8];
#pragma unroll
            for (int m = 0; m < 8; m++) {
                float e0 = __builtin_amdgcn_exp2f(c[2 * m]);
                float e1 = __builtin_amdgcn_exp2f(c[2 * m + 1]);
                la[2 * (m & 1)]     += e0;
                la[2 * (m & 1) + 1] += e1;
                union { h16x2 h; int i; } u;
                u.h = __builtin_amdgcn_cvt_pkrtz(e0, e1);
                pr[m] = u.i;
            }
            // pr[m]@hh holds keys (local): m0:{4hh,4hh+1} m1:{4hh+2,4hh+3}
            // m2:{8+4hh,..} m3:{10+4hh,..} m4..7: +16 of m0..3
#pragma unroll
            for (int t = 0; t < 2; t++) {
                int p0 = pr[4 * t + 0], p1 = pr[4 * t + 1];
                int p2 = pr[4 * t + 2], p3 = pr[4 * t + 3];
                int s0 = __shfl_xor(p0, 32, 64);
                int s1 = __shfl_xor(p1, 32, 64);
                int s2 = __shfl_xor(p2, 32, 64);
                int s3 = __shfl_xor(p3, 32, 64);
                union { int i[4]; f16x8 v; } bu;
                bu.i[0] = hh ? s2 : p0;   // keys hh*8 + {0,1}
                bu.i[1] = hh ? s3 : p1;   // keys hh*8 + {2,3}
                bu.i[2] = hh ? p2 : s0;   // keys hh*8 + {4,5}
                bu.i[3] = hh ? p3 : s1;   // keys hh*8 + {6,7}
                int ks = kbk * 2 + t;
#pragma unroll
                for (int db = 0; db < 2; db++) {
                    f16x8 vf = *(const f16x8*)&Vsc[off[db][ks]];
                    oacc[db] = __builtin_amdgcn_mfma_f32_32x32x16_f16(vf, bu.v, oacc[db], 0, 0, 0);
                }
            }
        }
        cur ^= 1;
    }

    // epilogue: lane holds q = qrow0+lq; oacc[db][r] -> d = db*32+(r&3)+8*(r>>2)+4hh
    float lacc = (la[0] + la[1]) + (la[2] + la[3]);
    float ltot = lacc + __shfl_xor(lacc, 32, 64);
    size_t rowb = ((size_t)(sp * 16 + bh) * 2048 + qrow0 + lq) * 64;
#pragma unroll
    for (int db = 0; db < 2; db++)
#pragma unroll
        for (int rq = 0; rq < 4; rq++) {
            f16x4 o4;
#pragma unroll
            for (int i = 0; i < 4; i++) o4[i] = (f16)oacc[db][rq * 4 + i];
            *(f16x4*)&Op[rowb + db * 32 + rq * 8 + hh * 4] = o4;
        }
    if (hh == 0)
        Lsum[(size_t)(sp * 16 + bh) * 2048 + qrow0 + lq] = ltot;
}

// ---------------------------------------------------------------------------
// Combine nsplit key-splits (shared implicit max -> plain sums). grid 8192x256.
// ---------------------------------------------------------------------------
__global__ __launch_bounds__(256)
void attn_combine(const f16* __restrict__ Op, const float* __restrict__ Lsum,
                  f16* __restrict__ O, int nsplit)
{
    int t = blockIdx.x * 256 + threadIdx.x;
    int d = t & 63;
    int q = (t >> 6) & 2047;
    int bh = t >> 17;
    int b = bh >> 3, h = bh & 7;
    float l = 0.f, val = 0.f;
#pragma unroll 4
    for (int s = 0; s < nsplit; s++) {
        l   += Lsum[(size_t)(s * 16 + bh) * 2048 + q];
        val += (float)Op[((size_t)(s * 16 + bh) * 2048 + q) * 64 + d];
    }
    O[((size_t)b * 2048 + q) * 512 + h * 64 + d] = (f16)(val / l);
}

// ---------------------------------------------------------------------------
extern "C" void kernel_launch(void* const* d_in, const int* in_sizes, int n_in,
                              void* d_out, int out_size, void* d_ws, size_t ws_size,
                              hipStream_t stream)
{
    (void)in_sizes; (void)n_in; (void)out_size; (void)ws_size;
    const float* x      = (const float*)d_in[0];
    const float* cross  = (const float*)d_in[1];
    const float* ca_wq  = (const float*)d_in[2];
    const float* ca_bq  = (const float*)d_in[3];
    const float* ca_wk  = (const float*)d_in[4];
    const float* ca_bk  = (const float*)d_in[5];
    const float* ca_wv  = (const float*)d_in[6];
    const float* ca_bv  = (const float*)d_in[7];
    const float* ca_wo  = (const float*)d_in[8];
    const float* ca_bo  = (const float*)d_in[9];
    const float* sa_wq  = (const float*)d_in[10];
    const float* sa_bq  = (const float*)d_in[11];
    const float* sa_wk  = (const float*)d_in[12];
    const float* sa_bk  = (const float*)d_in[13];
    const float* sa_wv  = (const float*)d_in[14];
    const float* sa_bv  = (const float*)d_in[15];
    const float* sa_wo  = (const float*)d_in[16];
    const float* sa_bo  = (const float*)d_in[17];
    const float* ln1_g  = (const float*)d_in[18];
    const float* ln1_b  = (const float*)d_in[19];
    const float* ln2_g  = (const float*)d_in[20];
    const float* ln2_b  = (const float*)d_in[21];
    const float* mlp_w1 = (const float*)d_in[22];
    const float* mlp_b1 = (const float*)d_in[23];
    const float* mlp_w2 = (const float*)d_in[24];
    const float* mlp_b2 = (const float*)d_in[25];
    float* out = (float*)d_out;

    // ---- workspace layout ----
    float* XC = (float*)d_ws;            // 2M f32
    float* Yb = XC + 2097152;            // 2M f32
    f16* fb   = (f16*)(Yb + 2097152);
    f16* xh     = fb;                    // 2M
    f16* crossh = xh + 2097152;          // 4M
    f16* xnh    = crossh + 4194304;      // 2M
    f16* xn2h   = xnh + 2097152;         // 2M
    f16* Qh     = xn2h + 2097152;        // 2M
    f16* Kh     = Qh + 2097152;          // 4M
    f16* Vh     = Kh + 4194304;          // 4M (unused; kept for layout stability)
    f16* Vtb    = Vh + 4194304;          // 4M
    f16* ctxh   = Vtb + 4194304;         // 2M
    f16* h1h    = ctxh + 2097152;        // 8M (reused as attention partials Op)
    f16* t_caq  = h1h + 8388608;
    f16* t_cak  = t_caq + 262144;
    f16* t_cav  = t_cak + 262144;
    f16* t_cao  = t_cav + 262144;
    f16* t_saq  = t_cao + 262144;
    f16* t_sak  = t_saq + 262144;
    f16* t_sav  = t_sak + 262144;
    f16* t_sao  = t_sav + 262144;
    f16* t_w1   = t_sao + 262144;        // 1M
    f16* t_w2   = t_w1 + 1048576;        // 1M
    float* Lsum = (float*)(t_w2 + 1048576);   // 131072 floats

    // MLP2 split-K partials: 4 x [4096][512] f32 = 32 MB, aliasing the dead
    // Qh..ctxh region (Qh/Kh/Vh/Vtb dead after self-attn; ctxh dead after
    // step d, which precedes MLP2).
    float* Pk = (float*)Qh;

    PrepArgs pa;
    pa.ws[0] = ca_wq; pa.wd[0] = t_caq;
    pa.ws[1] = ca_wk; pa.wd[1] = t_cak;
    pa.ws[2] = ca_wv; pa.wd[2] = t_cav;
    pa.ws[3] = ca_wo; pa.wd[3] = t_cao;
    pa.ws[4] = sa_wq; pa.wd[4] = t_saq;
    pa.ws[5] = sa_wk; pa.wd[5] = t_sak;
    pa.ws[6] = sa_wv; pa.wd[6] = t_sav;
    pa.ws[7] = sa_wo; pa.wd[7] = t_sao;
    pa.ws[8] = mlp_w1; pa.wd[8] = t_w1;
    pa.ws[9] = mlp_w2; pa.wd[9] = t_w2;
    pa.x = x; pa.xh = xh; pa.cross = cross; pa.ch = crossh;
    prep_all<<<10240, 256, 0, stream>>>(pa);

    // a) cross-attention (split-K x4; V written pre-transposed by the gemm)
    gemm64<<<dim3(8, 64), 256, 0, stream>>>(xh, t_caq, ca_bq, nullptr, nullptr, Qh,
                                            512, 512, 11, QSCALE);
    gemm_f16<<<dim3(8, 64), 256, 0, stream>>>(crossh, t_cak, ca_bk, ca_bv, nullptr, nullptr,
        nullptr, nullptr, Kh, nullptr, nullptr, Vtb, 1, 1024, 512, 512, 12, 1, 0, 0, 1.0f);
    attention_split<<<dim3(8, 8, 8), 512, 0, stream>>>(Qh, Kh, Vtb, h1h, Lsum, 4096, 2);
    attn_combine<<<8192, 256, 0, stream>>>(h1h, Lsum, ctxh, 4);
    gemm64<<<dim3(8, 64), 256, 0, stream>>>(ctxh, t_cao, ca_bo, nullptr, XC, nullptr,
                                            512, 512, 11, 1.0f);
    // b,c) LN1 + self-attention (fused QKV, Q pre-scaled; split-K x4)
    layernorm_f16<<<4096, 128, 0, stream>>>(XC, ln1_g, ln1_b, xnh);
    gemm_f16<<<dim3(12, 32), 256, 0, stream>>>(xnh, t_saq, sa_bq, sa_bk, sa_bv, nullptr,
        nullptr, nullptr, Qh, Kh, nullptr, Vtb, 2, 1536, 512, 512, 11, 1, 0, 0, QSCALE);
    attention_split<<<dim3(8, 8, 8), 512, 0, stream>>>(Qh, Kh, Vtb, h1h, Lsum, 2048, 2);
    attn_combine<<<8192, 256, 0, stream>>>(h1h, Lsum, ctxh, 4);
    // d) y = xc + xs
    gemm64<<<dim3(8, 64), 256, 0, stream>>>(ctxh, t_sao, sa_bo, XC, Yb, nullptr,
                                            512, 512, 11, 1.0f);
    // e,f) LN2 + GELU MLP (fast exact-erf GELU in the epilogue)
    layernorm_f16<<<4096, 128, 0, stream>>>(Yb, ln2_g, ln2_b, xn2h);
    gemm_f16<<<dim3(16, 32), 256, 0, stream>>>(xn2h, t_w1, mlp_b1, nullptr, nullptr, nullptr,
        nullptr, h1h, nullptr, nullptr, nullptr, nullptr, 0, 2048, 512, 512, 11, 0, 1, 0, 1.0f);
    // g) out = y + h1 @ w2 + b2: split-K x4 into f32 partials, then combine.
    gemm_f16<<<dim3(4, 32, 4), 256, 0, stream>>>(h1h, t_w2, nullptr, nullptr, nullptr, nullptr,
        Pk, nullptr, nullptr, nullptr, nullptr, nullptr, 0, 512, 512, 2048, 11, 0, 0,
        (size_t)2097152, 1.0f);
    mlp2_combine<<<2048, 256, 0, stream>>>(Pk, Yb, mlp_b2, out);
}